// Round 2
// baseline (16813.667 us; speedup 1.0000x reference)
//
#include <hip/hip_runtime.h>
#include <math.h>

#define Tlen  1024
#define Din   128
#define Hdim  256

typedef __attribute__((ext_vector_type(8)))  short short8;
typedef __attribute__((ext_vector_type(16))) short short16;
typedef __attribute__((ext_vector_type(4)))  float f32x4;

// ---------------- ws layout (bytes) ----------------
// [0,1024)           : pod flag arrays (pod p: 32 u32 at byte p*128), flag[m] = phases completed
// [1024, +1MB)       : parity-1 packed h planes (zeroed): h1 512KB then h2 512KB
//                      element = u32: low16 = bf16-hi, high16 = bf16-lo
// [1049600, +1MB)    : parity-0 packed h planes (written before read)
// [2098176, +768KB)  : W1-lo swizzled, per-hs slab 48 KB
// [2884608, +1MB)    : W2-lo swizzled, per-hs slab 64 KB
#define WS_BAR    0
#define WS_H      1024
#define WS_WLO1   2098176
#define WS_WLO2   2884608
#define ZERO_BYTES (1024 + 1048576)

__device__ __forceinline__ unsigned short f2bf(float f) {
    unsigned u = __float_as_uint(f);
    u += 0x7fffu + ((u >> 16) & 1u);
    return (unsigned short)(u >> 16);
}
__device__ __forceinline__ float bf2f(unsigned short s) {
    return __uint_as_float(((unsigned)s) << 16);
}
__device__ __forceinline__ float sigf(float x) { return 1.0f / (1.0f + __expf(-x)); }
__device__ __forceinline__ float tanh_(float x) {
    x = fminf(fmaxf(x, -15.0f), 15.0f);
    float e = __expf(2.0f * x);
    return (e - 1.0f) / (e + 1.0f);
}

#define MFMA3(g, AH, AL, BH, BL)                                                   \
    acc[g] = __builtin_amdgcn_mfma_f32_16x16x32_bf16(AH, BH, acc[g], 0, 0, 0);     \
    acc[g] = __builtin_amdgcn_mfma_f32_16x16x32_bf16(AL, BH, acc[g], 0, 0, 0);     \
    acc[g] = __builtin_amdgcn_mfma_f32_16x16x32_bf16(AH, BL, acc[g], 0, 0, 0);

// Unpack 4 u64 (8 packed u32) into hi/lo bf16 fragments.
#define UNPACK4(BUF, BASEI, AH, AL)                                                \
    {                                                                              \
        union { unsigned long long u[4]; short16 v; } t_;                          \
        t_.u[0] = BUF[(BASEI) + 0]; t_.u[1] = BUF[(BASEI) + 1];                    \
        t_.u[2] = BUF[(BASEI) + 2]; t_.u[3] = BUF[(BASEI) + 3];                    \
        AH = __builtin_shufflevector(t_.v, t_.v, 0, 2, 4, 6, 8, 10, 12, 14);       \
        AL = __builtin_shufflevector(t_.v, t_.v, 1, 3, 5, 7, 9, 11, 13, 15);       \
    }

__global__ __launch_bounds__(256, 1) void lstm_persist(
    const float* __restrict__ x,
    const float* __restrict__ W1, const float* __restrict__ b1,
    const float* __restrict__ W2, const float* __restrict__ b2,
    const float* __restrict__ Wout, const float* __restrict__ bout,
    float* __restrict__ out, char* __restrict__ wsb)
{
    __shared__ short8 whi[4096];   // 64 KB: [ks][gate][lane], 16B fragments

    const int tid    = threadIdx.x;
    const int pod    = blockIdx.x & 7;     // likely XCD-local under %8 mapping (perf only)
    const int member = blockIdx.x >> 3;    // 0..31
    const bool is_l1 = (member < 16);
    const int hs     = member & 15;
    const int NKS    = is_l1 ? 12 : 16;
    const float* Wraw = is_l1 ? W1 : W2;
    const float* bias = is_l1 ? b1 : b2;

    short8* blo = (short8*)(wsb + (is_l1 ? (WS_WLO1 + (size_t)hs * 49152)
                                         : (WS_WLO2 + (size_t)hs * 65536)));

    // ---- init: swizzle weight slice into fragment order: hi -> LDS, lo -> ws
    for (int t = tid; t < NKS * 256; t += 256) {
        const int lane = t & 63, g = (t >> 6) & 3, ks = t >> 8;
        const int q = lane >> 4, n = lane & 15;
        const int col = g * 256 + hs * 16 + n;
        short8 hv, lv;
#pragma unroll
        for (int j = 0; j < 8; ++j) {
            float v = Wraw[(size_t)(ks * 32 + q * 8 + j) * 1024 + col];
            unsigned short h = f2bf(v);
            hv[j] = (short)h;
            lv[j] = (short)f2bf(v - bf2f(h));
        }
        whi[t] = hv;
        blo[t] = lv;   // plain store; consumed only by this block (same CU/L2)
    }
    __syncthreads();

    const int w = tid >> 6, lane = tid & 63;
    const int q = lane >> 4, n = lane & 15;
    const int rowA = pod * 64 + w * 16 + n;

    float biasg[4];
#pragma unroll
    for (int g = 0; g < 4; ++g) biasg[g] = bias[g * 256 + hs * 16 + n];

    float creg[4] = {0.f, 0.f, 0.f, 0.f};
    unsigned* flags = (unsigned*)(wsb + WS_BAR) + pod * 32;  // 32 u32, one 128B line

    auto plane = [&](int par, int layer) -> unsigned* {
        return (unsigned*)(wsb + WS_H + (size_t)(par ^ 1) * 1048576 + (size_t)layer * 524288);
    };

    for (int p = 0; p <= Tlen; ++p) {
        f32x4 acc[4];
        const bool act_l1 = is_l1 && (p < Tlen);
        const bool act_l2 = (!is_l1) && (p >= 1);

        if (act_l1 || act_l2) {
#pragma unroll
            for (int g = 0; g < 4; ++g) {
                acc[g][0] = biasg[g]; acc[g][1] = biasg[g];
                acc[g][2] = biasg[g]; acc[g][3] = biasg[g];
            }
        }

        // ---- L1 part 1 (x-dependent, no barrier needed): ksteps 0..3
        if (act_l1) {
#pragma unroll
            for (int ks = 0; ks < 4; ++ks) {
                const int kk = ks * 32 + q * 8;
                const float* xp = x + (size_t)rowA * (size_t)(Tlen * Din) + (size_t)p * Din + kk;
                f32x4 v0 = *(const f32x4*)xp;
                f32x4 v1 = *(const f32x4*)(xp + 4);
                float vv[8] = {v0[0], v0[1], v0[2], v0[3], v1[0], v1[1], v1[2], v1[3]};
                short8 ah, al;
#pragma unroll
                for (int j = 0; j < 8; ++j) {
                    unsigned short h = f2bf(vv[j]);
                    ah[j] = (short)h;
                    al[j] = (short)f2bf(vv[j] - bf2f(h));
                }
#pragma unroll
                for (int g = 0; g < 4; ++g) {
                    short8 bh = whi[ks * 256 + g * 64 + lane];
                    short8 bl = blo[ks * 256 + g * 64 + lane];
                    MFMA3(g, ah, al, bh, bl)
                }
            }
        }

        // ---- wait for all 32 members of this pod to have finished phase p-1.
        // Parallel poll: wave 0's lanes each watch one flag word (one coalesced
        // 128B load per poll iteration), no RMW anywhere. s_sleep back-off keeps
        // polling traffic off the L2 while producers are storing.
        if (p > 0 && w == 0) {
            const unsigned tgt = (unsigned)p;
            const int fl = lane & 31;
            for (;;) {
                unsigned v = __hip_atomic_load(flags + fl, __ATOMIC_RELAXED,
                                               __HIP_MEMORY_SCOPE_AGENT);
                if (__all((int)(v >= tgt))) break;
                __builtin_amdgcn_s_sleep(1);
            }
        }
        __syncthreads();   // broadcast flag observation; block-local fence

        // ---- L1 part 2: h1[p-1]-dependent ksteps 4..11, epilogue
        if (act_l1) {
            const int s = p;
            const unsigned* h1o = plane((s + 1) & 1, 0);
            const unsigned long long* hb =
                (const unsigned long long*)(h1o + (size_t)rowA * Hdim);
            // Issue ALL 32 gather loads back-to-back (32 x 8B in flight),
            // then consume; compiler inserts partial vmcnt waits.
            unsigned long long buf[32];
#pragma unroll
            for (int i = 0; i < 32; ++i) {
                const int ks0 = i >> 2, j = i & 3;
                buf[i] = __hip_atomic_load(hb + ks0 * 16 + q * 4 + j,
                                           __ATOMIC_RELAXED, __HIP_MEMORY_SCOPE_AGENT);
            }
#pragma unroll
            for (int ks0 = 0; ks0 < 8; ++ks0) {
                short8 ah, al;
                UNPACK4(buf, ks0 * 4, ah, al)
                const int ks = ks0 + 4;
#pragma unroll
                for (int g = 0; g < 4; ++g) {
                    short8 bh = whi[ks * 256 + g * 64 + lane];
                    short8 bl = blo[ks * 256 + g * 64 + lane];
                    MFMA3(g, ah, al, bh, bl)
                }
            }
            unsigned* op = plane(s & 1, 0);
#pragma unroll
            for (int r = 0; r < 4; ++r) {
                float fg = acc[0][r], ig = acc[1][r], gg = acc[2][r], og = acc[3][r];
                float cn = sigf(fg) * creg[r] + sigf(ig) * tanh_(gg);
                creg[r] = cn;
                float hv = sigf(og) * tanh_(cn);
                const int row = pod * 64 + w * 16 + q * 4 + r;
                const int ci  = hs * 16 + n;
                unsigned short hh = f2bf(hv);
                unsigned short ll = f2bf(hv - bf2f(hh));
                unsigned word = (unsigned)hh | ((unsigned)ll << 16);
                __hip_atomic_store(op + (size_t)row * Hdim + ci, word,
                                   __ATOMIC_RELAXED, __HIP_MEMORY_SCOPE_AGENT);
            }
        }

        // ---- L2: step s=p-1, all ksteps gated on flags(p-1)
        if (act_l2) {
            const int s = p - 1;
            const unsigned* h1c = plane(s & 1, 0);        // h1[s], produced phase p-1
            const unsigned* h2o = plane((s + 1) & 1, 1);  // h2[s-1], produced phase p-1
            const unsigned long long* hb1 =
                (const unsigned long long*)(h1c + (size_t)rowA * Hdim);
            const unsigned long long* hb2 =
                (const unsigned long long*)(h2o + (size_t)rowA * Hdim);
            // Issue ALL 64 gather loads (64 x 8B = 128 VGPRs in flight) before
            // any consumption — full latency overlap.
            unsigned long long bufA[32], bufB[32];
#pragma unroll
            for (int i = 0; i < 32; ++i) {
                const int ks0 = i >> 2, j = i & 3;
                bufA[i] = __hip_atomic_load(hb1 + ks0 * 16 + q * 4 + j,
                                            __ATOMIC_RELAXED, __HIP_MEMORY_SCOPE_AGENT);
            }
#pragma unroll
            for (int i = 0; i < 32; ++i) {
                const int ks0 = i >> 2, j = i & 3;
                bufB[i] = __hip_atomic_load(hb2 + ks0 * 16 + q * 4 + j,
                                            __ATOMIC_RELAXED, __HIP_MEMORY_SCOPE_AGENT);
            }
#pragma unroll
            for (int ks = 0; ks < 8; ++ks) {
                short8 ah, al;
                UNPACK4(bufA, ks * 4, ah, al)
#pragma unroll
                for (int g = 0; g < 4; ++g) {
                    short8 bh = whi[ks * 256 + g * 64 + lane];
                    short8 bl = blo[ks * 256 + g * 64 + lane];
                    MFMA3(g, ah, al, bh, bl)
                }
            }
#pragma unroll
            for (int ks0 = 0; ks0 < 8; ++ks0) {
                short8 ah, al;
                UNPACK4(bufB, ks0 * 4, ah, al)
                const int ks = ks0 + 8;
#pragma unroll
                for (int g = 0; g < 4; ++g) {
                    short8 bh = whi[ks * 256 + g * 64 + lane];
                    short8 bl = blo[ks * 256 + g * 64 + lane];
                    MFMA3(g, ah, al, bh, bl)
                }
            }
            unsigned* op = plane(s & 1, 1);
#pragma unroll
            for (int r = 0; r < 4; ++r) {
                float fg = acc[0][r], ig = acc[1][r], gg = acc[2][r], og = acc[3][r];
                float cn = sigf(fg) * creg[r] + sigf(ig) * tanh_(gg);
                creg[r] = cn;
                float hv = sigf(og) * tanh_(cn);
                const int row = pod * 64 + w * 16 + q * 4 + r;
                const int ci  = hs * 16 + n;
                unsigned short hh = f2bf(hv);
                unsigned short ll = f2bf(hv - bf2f(hh));
                unsigned word = (unsigned)hh | ((unsigned)ll << 16);
                __hip_atomic_store(op + (size_t)row * Hdim + ci, word,
                                   __ATOMIC_RELAXED, __HIP_MEMORY_SCOPE_AGENT);
            }
        }

        // ---- arrive: __syncthreads drains each wave's vmcnt (write-through stores
        // reached the coherence point), then one plain flag store — no RMW, the 32
        // members' stores land in parallel on distinct words of one line.
        __syncthreads();
        if (tid == 0) {
            __hip_atomic_store(flags + member, (unsigned)(p + 1),
                               __ATOMIC_RELAXED, __HIP_MEMORY_SCOPE_AGENT);
        }
    }

    // ---- output projection (member-0 blocks): final h2 = step 1023, parity 1
    if (member == 0) {
        if (w == 0) {
            const unsigned tgt = (unsigned)(Tlen + 1);
            const int fl = lane & 31;
            for (;;) {
                unsigned v = __hip_atomic_load(flags + fl, __ATOMIC_RELAXED,
                                               __HIP_MEMORY_SCOPE_AGENT);
                if (__all((int)(v >= tgt))) break;
                __builtin_amdgcn_s_sleep(1);
            }
        }
        __syncthreads();
        const unsigned* h2f = plane(1, 1);
        const int r = tid >> 2, part = tid & 3;
        const int row = pod * 64 + r;
        float s = 0.f;
        for (int k = part * 64; k < part * 64 + 64; k += 2) {
            unsigned long long u = __hip_atomic_load(
                (const unsigned long long*)(h2f + (size_t)row * Hdim + k),
                __ATOMIC_RELAXED, __HIP_MEMORY_SCOPE_AGENT);
            unsigned w0 = (unsigned)u, w1 = (unsigned)(u >> 32);
            float hv0 = bf2f((unsigned short)(w0 & 0xffff)) + bf2f((unsigned short)(w0 >> 16));
            float hv1 = bf2f((unsigned short)(w1 & 0xffff)) + bf2f((unsigned short)(w1 >> 16));
            s += hv0 * Wout[k] + hv1 * Wout[k + 1];
        }
        s += __shfl_xor(s, 1);
        s += __shfl_xor(s, 2);
        if (part == 0) out[row] = s + bout[0];
    }
}

extern "C" void kernel_launch(void* const* d_in, const int* in_sizes, int n_in,
                              void* d_out, int out_size, void* d_ws, size_t ws_size,
                              hipStream_t stream)
{
    const float* x    = (const float*)d_in[0];
    const float* W1   = (const float*)d_in[1];
    const float* b1   = (const float*)d_in[2];
    const float* W2   = (const float*)d_in[3];
    const float* b2   = (const float*)d_in[4];
    const float* Wout = (const float*)d_in[5];
    const float* bout = (const float*)d_in[6];

    hipMemsetAsync(d_ws, 0, ZERO_BYTES, stream);
    lstm_persist<<<256, 256, 0, stream>>>(x, W1, b1, W2, b2, Wout, bout,
                                          (float*)d_out, (char*)d_ws);
}

// Round 3
// 13919.687 us; speedup vs baseline: 1.2079x; 1.2079x over previous
//
#include <hip/hip_runtime.h>
#include <math.h>

#define Tlen  1024
#define Din   128
#define Hdim  256

typedef __attribute__((ext_vector_type(8)))  short short8;
typedef __attribute__((ext_vector_type(16))) short short16;
typedef __attribute__((ext_vector_type(4)))  float f32x4;

// ---------------- ws layout (bytes) ----------------
// [0,1024)           : pod barrier counters (pod p at u32 offset p*32 = byte p*128)
// [1024, +1MB)       : parity-1 packed h planes (zeroed): h1 512KB then h2 512KB
//                      element = u32: low16 = bf16-hi, high16 = bf16-lo
// [1049600, +1MB)    : parity-0 packed h planes (written before read)
// [2098176, +768KB)  : W1-lo swizzled, per-hs slab 48 KB
// [2884608, +1MB)    : W2-lo swizzled, per-hs slab 64 KB
#define WS_BAR    0
#define WS_H      1024
#define WS_WLO1   2098176
#define WS_WLO2   2884608
#define ZERO_BYTES (1024 + 1048576)

__device__ __forceinline__ unsigned short f2bf(float f) {
    unsigned u = __float_as_uint(f);
    u += 0x7fffu + ((u >> 16) & 1u);
    return (unsigned short)(u >> 16);
}
__device__ __forceinline__ float bf2f(unsigned short s) {
    return __uint_as_float(((unsigned)s) << 16);
}
__device__ __forceinline__ float sigf(float x) { return 1.0f / (1.0f + __expf(-x)); }
__device__ __forceinline__ float tanh_(float x) {
    x = fminf(fmaxf(x, -15.0f), 15.0f);
    float e = __expf(2.0f * x);
    return (e - 1.0f) / (e + 1.0f);
}

#define MFMA3(g, AH, AL, BH, BL)                                                   \
    acc[g] = __builtin_amdgcn_mfma_f32_16x16x32_bf16(AH, BH, acc[g], 0, 0, 0);     \
    acc[g] = __builtin_amdgcn_mfma_f32_16x16x32_bf16(AL, BH, acc[g], 0, 0, 0);     \
    acc[g] = __builtin_amdgcn_mfma_f32_16x16x32_bf16(AH, BL, acc[g], 0, 0, 0);

// Unpack one group (4 u64 = 8 packed u32) into hi/lo bf16 fragments.
#define UNPACK4G(GRP, AH, AL)                                                      \
    {                                                                              \
        union { unsigned long long u[4]; short16 v; } t_;                          \
        t_.u[0] = (GRP)[0]; t_.u[1] = (GRP)[1];                                    \
        t_.u[2] = (GRP)[2]; t_.u[3] = (GRP)[3];                                    \
        AH = __builtin_shufflevector(t_.v, t_.v, 0, 2, 4, 6, 8, 10, 12, 14);       \
        AL = __builtin_shufflevector(t_.v, t_.v, 1, 3, 5, 7, 9, 11, 13, 15);       \
    }

// Issue one group's 4 x 8B agent-scope loads (program-ordered, stay in VGPRs).
#define ISSUE4G(DST, SRC, OFF)                                                     \
    {                                                                              \
        (DST)[0] = __hip_atomic_load((SRC) + (OFF) + 0, __ATOMIC_RELAXED,          \
                                     __HIP_MEMORY_SCOPE_AGENT);                    \
        (DST)[1] = __hip_atomic_load((SRC) + (OFF) + 1, __ATOMIC_RELAXED,          \
                                     __HIP_MEMORY_SCOPE_AGENT);                    \
        (DST)[2] = __hip_atomic_load((SRC) + (OFF) + 2, __ATOMIC_RELAXED,          \
                                     __HIP_MEMORY_SCOPE_AGENT);                    \
        (DST)[3] = __hip_atomic_load((SRC) + (OFF) + 3, __ATOMIC_RELAXED,          \
                                     __HIP_MEMORY_SCOPE_AGENT);                    \
    }

__global__ __launch_bounds__(256, 1) void lstm_persist(
    const float* __restrict__ x,
    const float* __restrict__ W1, const float* __restrict__ b1,
    const float* __restrict__ W2, const float* __restrict__ b2,
    const float* __restrict__ Wout, const float* __restrict__ bout,
    float* __restrict__ out, char* __restrict__ wsb)
{
    __shared__ short8 whi[4096];   // 64 KB: [ks][gate][lane], 16B fragments

    const int tid    = threadIdx.x;
    const int pod    = blockIdx.x & 7;     // likely XCD-local under %8 mapping (perf only)
    const int member = blockIdx.x >> 3;    // 0..31
    const bool is_l1 = (member < 16);
    const int hs     = member & 15;
    const int NKS    = is_l1 ? 12 : 16;
    const float* Wraw = is_l1 ? W1 : W2;
    const float* bias = is_l1 ? b1 : b2;

    short8* blo = (short8*)(wsb + (is_l1 ? (WS_WLO1 + (size_t)hs * 49152)
                                         : (WS_WLO2 + (size_t)hs * 65536)));

    // ---- init: swizzle weight slice into fragment order: hi -> LDS, lo -> ws
    for (int t = tid; t < NKS * 256; t += 256) {
        const int lane = t & 63, g = (t >> 6) & 3, ks = t >> 8;
        const int q = lane >> 4, n = lane & 15;
        const int col = g * 256 + hs * 16 + n;
        short8 hv, lv;
#pragma unroll
        for (int j = 0; j < 8; ++j) {
            float v = Wraw[(size_t)(ks * 32 + q * 8 + j) * 1024 + col];
            unsigned short h = f2bf(v);
            hv[j] = (short)h;
            lv[j] = (short)f2bf(v - bf2f(h));
        }
        whi[t] = hv;
        blo[t] = lv;   // plain store; consumed only by this block (same CU/L2)
    }
    __syncthreads();

    const int w = tid >> 6, lane = tid & 63;
    const int q = lane >> 4, n = lane & 15;
    const int rowA = pod * 64 + w * 16 + n;

    float biasg[4];
#pragma unroll
    for (int g = 0; g < 4; ++g) biasg[g] = bias[g * 256 + hs * 16 + n];

    float creg[4] = {0.f, 0.f, 0.f, 0.f};
    unsigned* bar = (unsigned*)(wsb + WS_BAR) + pod * 32;

    auto plane = [&](int par, int layer) -> unsigned* {
        return (unsigned*)(wsb + WS_H + (size_t)(par ^ 1) * 1048576 + (size_t)layer * 524288);
    };

    for (int p = 0; p <= Tlen; ++p) {
        f32x4 acc[4];
        const bool act_l1 = is_l1 && (p < Tlen);
        const bool act_l2 = (!is_l1) && (p >= 1);

        if (act_l1 || act_l2) {
#pragma unroll
            for (int g = 0; g < 4; ++g) {
                acc[g][0] = biasg[g]; acc[g][1] = biasg[g];
                acc[g][2] = biasg[g]; acc[g][3] = biasg[g];
            }
        }

        // ---- L1 part 1 (x-dependent, no barrier needed): ksteps 0..3
        if (act_l1) {
#pragma unroll
            for (int ks = 0; ks < 4; ++ks) {
                const int kk = ks * 32 + q * 8;
                const float* xp = x + (size_t)rowA * (size_t)(Tlen * Din) + (size_t)p * Din + kk;
                f32x4 v0 = *(const f32x4*)xp;
                f32x4 v1 = *(const f32x4*)(xp + 4);
                float vv[8] = {v0[0], v0[1], v0[2], v0[3], v1[0], v1[1], v1[2], v1[3]};
                short8 ah, al;
#pragma unroll
                for (int j = 0; j < 8; ++j) {
                    unsigned short h = f2bf(vv[j]);
                    ah[j] = (short)h;
                    al[j] = (short)f2bf(vv[j] - bf2f(h));
                }
#pragma unroll
                for (int g = 0; g < 4; ++g) {
                    short8 bh = whi[ks * 256 + g * 64 + lane];
                    short8 bl = blo[ks * 256 + g * 64 + lane];
                    MFMA3(g, ah, al, bh, bl)
                }
            }
        }

        // ---- wait for barrier of phase p-1 (relaxed spin; no cache maintenance)
        if (tid == 0 && p > 0) {
            const unsigned tgt = 32u * (unsigned)p;
            while (__hip_atomic_load(bar, __ATOMIC_RELAXED, __HIP_MEMORY_SCOPE_AGENT) < tgt) {}
        }
        __syncthreads();   // broadcast barrier completion; full memory fence for block

        // ---- L1 part 2: h1[p-1]-dependent ksteps 4..11
        // Software-pipelined gather: prefetch distance 3 groups (12 loads in
        // flight), ring of 4 x (4 u64) = 32 VGPRs live — bounded, no spill.
        if (act_l1) {
            const int s = p;
            const unsigned* h1o = plane((s + 1) & 1, 0);
            const unsigned long long* hb =
                (const unsigned long long*)(h1o + (size_t)rowA * Hdim);
            unsigned long long pb[4][4];
#pragma unroll
            for (int g = 0; g < 3; ++g) {
                ISSUE4G(pb[g], hb, g * 16 + q * 4)
            }
#pragma unroll
            for (int g = 0; g < 8; ++g) {
                if (g + 3 < 8) {
                    ISSUE4G(pb[(g + 3) & 3], hb, (g + 3) * 16 + q * 4)
                }
                short8 ah, al;
                UNPACK4G(pb[g & 3], ah, al)
                const int ks = g + 4;
#pragma unroll
                for (int gt = 0; gt < 4; ++gt) {
                    short8 bh = whi[ks * 256 + gt * 64 + lane];
                    short8 bl = blo[ks * 256 + gt * 64 + lane];
                    MFMA3(gt, ah, al, bh, bl)
                }
            }
            unsigned* op = plane(s & 1, 0);
#pragma unroll
            for (int r = 0; r < 4; ++r) {
                float fg = acc[0][r], ig = acc[1][r], gg = acc[2][r], og = acc[3][r];
                float cn = sigf(fg) * creg[r] + sigf(ig) * tanh_(gg);
                creg[r] = cn;
                float hv = sigf(og) * tanh_(cn);
                const int row = pod * 64 + w * 16 + q * 4 + r;
                const int ci  = hs * 16 + n;
                unsigned short hh = f2bf(hv);
                unsigned short ll = f2bf(hv - bf2f(hh));
                unsigned word = (unsigned)hh | ((unsigned)ll << 16);
                __hip_atomic_store(op + (size_t)row * Hdim + ci, word,
                                   __ATOMIC_RELAXED, __HIP_MEMORY_SCOPE_AGENT);
            }
        }

        // ---- L2: step s=p-1, 16 k-groups (8 from h1[s], 8 from h2[s-1]),
        // same depth-3 pipelined gather across the concatenated group sequence.
        if (act_l2) {
            const int s = p - 1;
            const unsigned* h1c = plane(s & 1, 0);        // h1[s], produced phase p-1
            const unsigned* h2o = plane((s + 1) & 1, 1);  // h2[s-1], produced phase p-1
            const unsigned long long* hb1 =
                (const unsigned long long*)(h1c + (size_t)rowA * Hdim);
            const unsigned long long* hb2 =
                (const unsigned long long*)(h2o + (size_t)rowA * Hdim);
            unsigned long long pb[4][4];
#pragma unroll
            for (int g = 0; g < 3; ++g) {
                ISSUE4G(pb[g], hb1, g * 16 + q * 4)
            }
#pragma unroll
            for (int g = 0; g < 16; ++g) {
                if (g + 3 < 16) {
                    const int gg = g + 3;
                    if (gg < 8) {
                        ISSUE4G(pb[gg & 3], hb1, gg * 16 + q * 4)
                    } else {
                        ISSUE4G(pb[gg & 3], hb2, (gg - 8) * 16 + q * 4)
                    }
                }
                short8 ah, al;
                UNPACK4G(pb[g & 3], ah, al)
                const int ks = g;
#pragma unroll
                for (int gt = 0; gt < 4; ++gt) {
                    short8 bh = whi[ks * 256 + gt * 64 + lane];
                    short8 bl = blo[ks * 256 + gt * 64 + lane];
                    MFMA3(gt, ah, al, bh, bl)
                }
            }
            unsigned* op = plane(s & 1, 1);
#pragma unroll
            for (int r = 0; r < 4; ++r) {
                float fg = acc[0][r], ig = acc[1][r], gg = acc[2][r], og = acc[3][r];
                float cn = sigf(fg) * creg[r] + sigf(ig) * tanh_(gg);
                creg[r] = cn;
                float hv = sigf(og) * tanh_(cn);
                const int row = pod * 64 + w * 16 + q * 4 + r;
                const int ci  = hs * 16 + n;
                unsigned short hh = f2bf(hv);
                unsigned short ll = f2bf(hv - bf2f(hh));
                unsigned word = (unsigned)hh | ((unsigned)ll << 16);
                __hip_atomic_store(op + (size_t)row * Hdim + ci, word,
                                   __ATOMIC_RELAXED, __HIP_MEMORY_SCOPE_AGENT);
            }
        }

        // ---- arrive: __syncthreads drains each wave's vmcnt (write-through stores
        // are at the coherence point), then one relaxed add.
        __syncthreads();
        if (tid == 0) {
            __hip_atomic_fetch_add(bar, 1u, __ATOMIC_RELAXED, __HIP_MEMORY_SCOPE_AGENT);
        }
    }

    // ---- output projection (member-0 blocks): final h2 = step 1023, parity 1
    if (member == 0) {
        if (tid == 0) {
            const unsigned tgt = 32u * (unsigned)(Tlen + 1);
            while (__hip_atomic_load(bar, __ATOMIC_RELAXED, __HIP_MEMORY_SCOPE_AGENT) < tgt) {}
        }
        __syncthreads();
        const unsigned* h2f = plane(1, 1);
        const int r = tid >> 2, part = tid & 3;
        const int row = pod * 64 + r;
        float s = 0.f;
        for (int k = part * 64; k < part * 64 + 64; k += 2) {
            unsigned long long u = __hip_atomic_load(
                (const unsigned long long*)(h2f + (size_t)row * Hdim + k),
                __ATOMIC_RELAXED, __HIP_MEMORY_SCOPE_AGENT);
            unsigned w0 = (unsigned)u, w1 = (unsigned)(u >> 32);
            float hv0 = bf2f((unsigned short)(w0 & 0xffff)) + bf2f((unsigned short)(w0 >> 16));
            float hv1 = bf2f((unsigned short)(w1 & 0xffff)) + bf2f((unsigned short)(w1 >> 16));
            s += hv0 * Wout[k] + hv1 * Wout[k + 1];
        }
        s += __shfl_xor(s, 1);
        s += __shfl_xor(s, 2);
        if (part == 0) out[row] = s + bout[0];
    }
}

extern "C" void kernel_launch(void* const* d_in, const int* in_sizes, int n_in,
                              void* d_out, int out_size, void* d_ws, size_t ws_size,
                              hipStream_t stream)
{
    const float* x    = (const float*)d_in[0];
    const float* W1   = (const float*)d_in[1];
    const float* b1   = (const float*)d_in[2];
    const float* W2   = (const float*)d_in[3];
    const float* b2   = (const float*)d_in[4];
    const float* Wout = (const float*)d_in[5];
    const float* bout = (const float*)d_in[6];

    hipMemsetAsync(d_ws, 0, ZERO_BYTES, stream);
    lstm_persist<<<256, 256, 0, stream>>>(x, W1, b1, W2, b2, Wout, bout,
                                          (float*)d_out, (char*)d_ws);
}